// Round 5
// baseline (254.107 us; speedup 1.0000x reference)
//
#include <hip/hip_runtime.h>
#include <cstddef>
#include <cstdint>

#define NB 4
#define S_LEN 2048
#define DK 1024

typedef __attribute__((ext_vector_type(8))) short short8;       // 8 bf16 = 4 VGPR (MFMA A/B frag)
typedef __attribute__((ext_vector_type(4))) float floatx4;      // MFMA C/D frag
typedef __attribute__((ext_vector_type(4))) unsigned short ushort4v;
typedef __attribute__((ext_vector_type(8))) unsigned short ushort8v;

__device__ inline unsigned short f2bf(float f) {
    unsigned int u = __float_as_uint(f);
    u += 0x7fff + ((u >> 16) & 1);   // round-to-nearest-even
    return (unsigned short)(u >> 16);
}
__device__ inline float bf2f(unsigned short u) {
    return __uint_as_float(((unsigned int)u) << 16);
}

#define GLD16(gp, lp)                                                                  \
    __builtin_amdgcn_global_load_lds(                                                  \
        (const __attribute__((address_space(1))) unsigned int*)(gp),                   \
        (__attribute__((address_space(3))) unsigned int*)(lp), 16, 0, 0)

// Stage a 128x64 bf16 tile into LDS with XOR swizzle: LDS[row][pg] holds
// global colgroup (pg ^ (row&7)) (colgroups of 8 el).  Fragment reads use
// pg = cg ^ (row&7), spreading the 16 m-lanes across 8 bank groups.
__device__ inline void stage128x64(const unsigned short* __restrict__ g, size_t ld,
                                   unsigned short* __restrict__ lds,
                                   int w, int lane)
{
    const int r8 = lane >> 3;                  // 0..7
    const int cg = (lane & 7) ^ r8;            // swizzled source colgroup
    const unsigned short* gp = g + (size_t)(w * 8 + r8) * ld + cg * 8;
    unsigned short* lp = lds + (size_t)(w * 8) * 64;
    #pragma unroll
    for (int seg = 0; seg < 4; ++seg)
        GLD16(gp + (size_t)(seg * 32) * ld, lp + (size_t)seg * 32 * 64);
}

// ---------------------------------------------------------------------------
// K0: cast fp32 -> bf16 for x, Wq, Wk, Wv
// ---------------------------------------------------------------------------
__global__ __launch_bounds__(256) void cast_all(
    const float* __restrict__ x, const float* __restrict__ Wq,
    const float* __restrict__ Wk, const float* __restrict__ Wv,
    unsigned short* __restrict__ xb, unsigned short* __restrict__ wqb,
    unsigned short* __restrict__ wkb, unsigned short* __restrict__ wvb)
{
    const float* src; unsigned short* dst; int n4;
    if (blockIdx.z == 0)      { src = x;  dst = xb;  n4 = (int)((size_t)NB * S_LEN * DK / 4); }
    else if (blockIdx.z == 1) { src = Wq; dst = wqb; n4 = DK * DK / 4; }
    else if (blockIdx.z == 2) { src = Wk; dst = wkb; n4 = DK * DK / 4; }
    else                      { src = Wv; dst = wvb; n4 = DK * DK / 4; }
    const int stride = gridDim.x * 256;
    for (int i = blockIdx.x * 256 + threadIdx.x; i < n4; i += stride) {
        float4 f = ((const float4*)src)[i];
        ushort4v o;
        o.x = f2bf(f.x); o.y = f2bf(f.y); o.z = f2bf(f.z); o.w = f2bf(f.w);
        ((ushort4v*)dst)[i] = o;
    }
}

// ---------------------------------------------------------------------------
// K1: fused QKV projection, bf16 MFMA, 128x128 tile, BK=64, swizzled LDS.
// z==2 (v) writes TRANSPOSED vT[b][o][s].
// ---------------------------------------------------------------------------
__global__ __launch_bounds__(256) void qkv_mfma(
    const unsigned short* __restrict__ xb,
    const unsigned short* __restrict__ wqb, const unsigned short* __restrict__ wkb,
    const unsigned short* __restrict__ wvb,
    const float* __restrict__ bq, const float* __restrict__ bk, const float* __restrict__ bv,
    unsigned short* __restrict__ qb, unsigned short* __restrict__ kb,
    unsigned short* __restrict__ vTb)
{
    __shared__ unsigned short As[128 * 64];
    __shared__ unsigned short Bs[128 * 64];
    const int tid  = threadIdx.x;
    const int w    = tid >> 6, lane = tid & 63;
    const int lm   = lane & 15, quad = lane >> 4;
    const int xr   = lm & 7;                   // row&7 of every fragment row this lane reads
    const int m0   = blockIdx.x * 128, n0 = blockIdx.y * 128;
    const int z    = blockIdx.z;
    const unsigned short* Wb = (z == 0) ? wqb : (z == 1) ? wkb : wvb;
    const float* bias        = (z == 0) ? bq  : (z == 1) ? bk  : bv;

    const unsigned short* Ag = xb + (size_t)m0 * DK;
    const unsigned short* Bg = Wb + (size_t)n0 * DK;

    const int wr = (w >> 1) * 64, wc = (w & 1) * 64;

    floatx4 acc[4][4];
    #pragma unroll
    for (int r = 0; r < 4; ++r)
        #pragma unroll
        for (int c = 0; c < 4; ++c) acc[r][c] = (floatx4)0.0f;

    for (int k0 = 0; k0 < DK; k0 += 64) {
        stage128x64(Ag + k0, DK, As, w, lane);
        stage128x64(Bg + k0, DK, Bs, w, lane);
        __syncthreads();
        #pragma unroll
        for (int ks = 0; ks < 2; ++ks) {
            short8 af[4], bf[4];
            #pragma unroll
            for (int r = 0; r < 4; ++r)
                af[r] = *(const short8*)&As[(size_t)(wr + r*16 + lm) * 64 + ((((ks<<2)|quad) ^ xr) << 3)];
            #pragma unroll
            for (int c = 0; c < 4; ++c)
                bf[c] = *(const short8*)&Bs[(size_t)(wc + c*16 + lm) * 64 + ((((ks<<2)|quad) ^ xr) << 3)];
            #pragma unroll
            for (int r = 0; r < 4; ++r)
                #pragma unroll
                for (int c = 0; c < 4; ++c)
                    acc[r][c] = __builtin_amdgcn_mfma_f32_16x16x32_bf16(af[r], bf[c], acc[r][c], 0, 0, 0);
        }
        __syncthreads();
    }

    if (z < 2) {
        unsigned short* out = (z == 0) ? qb : kb;
        #pragma unroll
        for (int r = 0; r < 4; ++r) {
            const int gm = m0 + wr + r * 16 + quad * 4;
            #pragma unroll
            for (int c = 0; c < 4; ++c) {
                const int gn = n0 + wc + c * 16 + lm;
                const float bb = bias[gn];
                #pragma unroll
                for (int e = 0; e < 4; ++e)
                    out[(size_t)(gm + e) * DK + gn] = f2bf(acc[r][c][e] + bb);
            }
        }
    } else {
        const int bidx = m0 >> 11;              // 128-tile never crosses a batch
        #pragma unroll
        for (int r = 0; r < 4; ++r) {
            const int gm = m0 + wr + r * 16 + quad * 4;
            const int sm = gm & (S_LEN - 1);
            #pragma unroll
            for (int c = 0; c < 4; ++c) {
                const int gn = n0 + wc + c * 16 + lm;
                const float bb = bias[gn];
                ushort4v pk;
                pk.x = f2bf(acc[r][c][0] + bb);
                pk.y = f2bf(acc[r][c][1] + bb);
                pk.z = f2bf(acc[r][c][2] + bb);
                pk.w = f2bf(acc[r][c][3] + bb);
                *(ushort4v*)&vTb[((size_t)bidx * DK + gn) * S_LEN + sm] = pk;
            }
        }
    }
}

// ---------------------------------------------------------------------------
// K2: scores -> unnormalized probabilities u, bf16 out.
// Compact triangular grid: blockIdx.x = t in [0,136) maps to (bi,bj), bj<=bi.
// Epilogue writes u = exp(s/32) with:
//   j >  i          : 0   (causal)
//   i >= len, j <= i: 1   (-> uniform after row normalization; fp32-exact-tie
//                          semantics of the reference's additive -1e9 mask)
// Coverage is all lower-triangle tiles, length-INDEPENDENT.
// ---------------------------------------------------------------------------
__global__ __launch_bounds__(256) void score_mfma(
    const unsigned short* __restrict__ qb, const unsigned short* __restrict__ kb,
    unsigned short* __restrict__ ub, const int* __restrict__ lengths)
{
    const int t = blockIdx.x, b = blockIdx.y;
    int bi = (int)((sqrtf(8.0f * t + 1.0f) - 1.0f) * 0.5f);
    while ((bi + 1) * (bi + 2) / 2 <= t) ++bi;
    while (bi * (bi + 1) / 2 > t) --bi;
    const int bj = t - bi * (bi + 1) / 2;
    const int m0 = bi * 128, n0 = bj * 128;
    const int len = lengths[b];

    __shared__ unsigned short As[128 * 64];
    __shared__ unsigned short Bs[128 * 64];
    const int tid  = threadIdx.x;
    const int w    = tid >> 6, lane = tid & 63;
    const int lm   = lane & 15, quad = lane >> 4;
    const int xr   = lm & 7;
    const unsigned short* Ag = qb + (size_t)b * S_LEN * DK + (size_t)m0 * DK;
    const unsigned short* Bg = kb + (size_t)b * S_LEN * DK + (size_t)n0 * DK;
    unsigned short* Ub = ub + (size_t)b * S_LEN * S_LEN;

    const int wr = (w >> 1) * 64, wc = (w & 1) * 64;

    floatx4 acc[4][4];
    #pragma unroll
    for (int r = 0; r < 4; ++r)
        #pragma unroll
        for (int c = 0; c < 4; ++c) acc[r][c] = (floatx4)0.0f;

    for (int k0 = 0; k0 < DK; k0 += 64) {
        stage128x64(Ag + k0, DK, As, w, lane);
        stage128x64(Bg + k0, DK, Bs, w, lane);
        __syncthreads();
        #pragma unroll
        for (int ks = 0; ks < 2; ++ks) {
            short8 af[4], bf[4];
            #pragma unroll
            for (int r = 0; r < 4; ++r)
                af[r] = *(const short8*)&As[(size_t)(wr + r*16 + lm) * 64 + ((((ks<<2)|quad) ^ xr) << 3)];
            #pragma unroll
            for (int c = 0; c < 4; ++c)
                bf[c] = *(const short8*)&Bs[(size_t)(wc + c*16 + lm) * 64 + ((((ks<<2)|quad) ^ xr) << 3)];
            #pragma unroll
            for (int r = 0; r < 4; ++r)
                #pragma unroll
                for (int c = 0; c < 4; ++c)
                    acc[r][c] = __builtin_amdgcn_mfma_f32_16x16x32_bf16(af[r], bf[c], acc[r][c], 0, 0, 0);
        }
        __syncthreads();
    }

    #pragma unroll
    for (int r = 0; r < 4; ++r) {
        const int gm = m0 + wr + r * 16 + quad * 4;
        #pragma unroll
        for (int c = 0; c < 4; ++c) {
            const int gn = n0 + wc + c * 16 + lm;
            #pragma unroll
            for (int e = 0; e < 4; ++e) {
                const int i = gm + e;
                float u;
                if (gn > i)          u = 0.0f;
                else if (i >= len)   u = 1.0f;
                else                 u = __expf(acc[r][c][e] * 0.03125f);
                Ub[(size_t)i * S_LEN + gn] = f2bf(u);
            }
        }
    }
}

// ---------------------------------------------------------------------------
// K3: deterministic per-row sum of u over [0, jend) -> inv_l[row] = 1/sum.
// jend = ceil((i+1)/128)*128 == exactly the tile-covered prefix; u is zero
// between nv and jend (causal zeros), so the sum is exact.
// ---------------------------------------------------------------------------
__global__ __launch_bounds__(256) void row_sum(
    const unsigned short* __restrict__ ub, float* __restrict__ inv_l)
{
    const int row = blockIdx.x;              // 0 .. B*S-1
    const int i = row & (S_LEN - 1);
    const int jend = ((i >> 7) + 1) << 7;
    const unsigned short* p = ub + (size_t)row * S_LEN;
    const int t = threadIdx.x;
    const int j0 = t * 8;

    float s = 0.0f;
    if (j0 < jend) {
        ushort8v raw = *(const ushort8v*)&p[j0];
        #pragma unroll
        for (int e = 0; e < 8; ++e) s += bf2f(raw[e]);
    }

    __shared__ float red[256];
    red[t] = s; __syncthreads();
    #pragma unroll
    for (int s2 = 128; s2 > 0; s2 >>= 1) {
        if (t < s2) red[t] += red[t + s2];
        __syncthreads();
    }
    if (t == 0) inv_l[row] = 1.0f / red[0];
}

// ---------------------------------------------------------------------------
// K4: O[b][i][o] = inv_l[b*S+i] * sum_j u[b][i][j] vT[b][o][j], bf16 MFMA.
// K-loop capped at (bi+1)*128 (u zero for j>i within that range).
// ---------------------------------------------------------------------------
__global__ __launch_bounds__(256) void pv_mfma(
    const unsigned short* __restrict__ ub, const unsigned short* __restrict__ vTb,
    const float* __restrict__ inv_l, float* __restrict__ out)
{
    __shared__ unsigned short As[128 * 64];
    __shared__ unsigned short Bs[128 * 64];
    const int tid  = threadIdx.x;
    const int w    = tid >> 6, lane = tid & 63;
    const int lm   = lane & 15, quad = lane >> 4;
    const int xr   = lm & 7;
    const int bi = blockIdx.x, bn = blockIdx.y, b = blockIdx.z;
    const int m0 = bi * 128, n0 = bn * 128;
    const unsigned short* Ag = ub  + (size_t)b * S_LEN * S_LEN + (size_t)m0 * S_LEN;
    const unsigned short* Bg = vTb + (size_t)b * DK * S_LEN    + (size_t)n0 * S_LEN;

    const int wr = (w >> 1) * 64, wc = (w & 1) * 64;
    const int kend = (bi + 1) * 128;

    floatx4 acc[4][4];
    #pragma unroll
    for (int r = 0; r < 4; ++r)
        #pragma unroll
        for (int c = 0; c < 4; ++c) acc[r][c] = (floatx4)0.0f;

    for (int k0 = 0; k0 < kend; k0 += 64) {
        stage128x64(Ag + k0, S_LEN, As, w, lane);
        stage128x64(Bg + k0, S_LEN, Bs, w, lane);
        __syncthreads();
        #pragma unroll
        for (int ks = 0; ks < 2; ++ks) {
            short8 af[4], bf[4];
            #pragma unroll
            for (int r = 0; r < 4; ++r)
                af[r] = *(const short8*)&As[(size_t)(wr + r*16 + lm) * 64 + ((((ks<<2)|quad) ^ xr) << 3)];
            #pragma unroll
            for (int c = 0; c < 4; ++c)
                bf[c] = *(const short8*)&Bs[(size_t)(wc + c*16 + lm) * 64 + ((((ks<<2)|quad) ^ xr) << 3)];
            #pragma unroll
            for (int r = 0; r < 4; ++r)
                #pragma unroll
                for (int c = 0; c < 4; ++c)
                    acc[r][c] = __builtin_amdgcn_mfma_f32_16x16x32_bf16(af[r], bf[c], acc[r][c], 0, 0, 0);
        }
        __syncthreads();
    }

    #pragma unroll
    for (int r = 0; r < 4; ++r) {
        const int gm = m0 + wr + r * 16 + quad * 4;
        const float4 il = *(const float4*)&inv_l[(size_t)b * S_LEN + gm];
        const float ilv[4] = {il.x, il.y, il.z, il.w};
        #pragma unroll
        for (int c = 0; c < 4; ++c) {
            const int gn = n0 + wc + c * 16 + lm;
            #pragma unroll
            for (int e = 0; e < 4; ++e)
                out[((size_t)b * S_LEN + gm + e) * DK + gn] = acc[r][c][e] * ilv[e];
        }
    }
}

// ---------------------------------------------------------------------------
extern "C" void kernel_launch(void* const* d_in, const int* in_sizes, int n_in,
                              void* d_out, int out_size, void* d_ws, size_t ws_size,
                              hipStream_t stream)
{
    const float* x  = (const float*)d_in[0];
    const float* Wq = (const float*)d_in[1];
    const float* bq = (const float*)d_in[2];
    const float* Wk = (const float*)d_in[3];
    const float* bk = (const float*)d_in[4];
    const float* Wv = (const float*)d_in[5];
    const float* bv = (const float*)d_in[6];
    const int* lengths = (const int*)d_in[7];
    float* out = (float*)d_out;

    // workspace (bf16 elements): qb | kb | vTb | xb | Wqb | Wkb | Wvb | ub | inv_l
    const size_t NQ = (size_t)NB * S_LEN * DK;       // 8388608
    const size_t NW = (size_t)DK * DK;               // 1048576
    const size_t NP = (size_t)NB * S_LEN * S_LEN;    // 16777216
    unsigned short* ws16 = (unsigned short*)d_ws;
    unsigned short* qb  = ws16;
    unsigned short* kb_ = ws16 + NQ;
    unsigned short* vTb = ws16 + 2 * NQ;
    unsigned short* xb  = ws16 + 3 * NQ;
    unsigned short* wqb = ws16 + 4 * NQ;
    unsigned short* wkb = wqb + NW;
    unsigned short* wvb = wkb + NW;
    unsigned short* ub  = ws16 + 4 * NQ + 3 * NW;    // bf16 unnormalized probs
    float* inv_l = (float*)(ub + NP);                // 8192 fp32

    cast_all<<<dim3(1024, 1, 4), 256, 0, stream>>>(x, Wq, Wk, Wv, xb, wqb, wkb, wvb);
    qkv_mfma<<<dim3(64, 8, 3), 256, 0, stream>>>(xb, wqb, wkb, wvb, bq, bk, bv, qb, kb_, vTb);
    score_mfma<<<dim3(136, NB), 256, 0, stream>>>(qb, kb_, ub, lengths);
    row_sum<<<dim3(NB * S_LEN), 256, 0, stream>>>(ub, inv_l);
    pv_mfma<<<dim3(16, 8, NB), 256, 0, stream>>>(ub, vTb, inv_l, out);
}

// Round 6
// 227.305 us; speedup vs baseline: 1.1179x; 1.1179x over previous
//
#include <hip/hip_runtime.h>
#include <cstddef>
#include <cstdint>

#define NB 4
#define S_LEN 2048
#define DK 1024

typedef __attribute__((ext_vector_type(8))) short short8;       // 8 bf16 = 4 VGPR (MFMA A/B frag)
typedef __attribute__((ext_vector_type(4))) float floatx4;      // MFMA C/D frag
typedef __attribute__((ext_vector_type(4))) unsigned short ushort4v;
typedef __attribute__((ext_vector_type(8))) unsigned short ushort8v;

__device__ inline unsigned short f2bf(float f) {
    unsigned int u = __float_as_uint(f);
    u += 0x7fff + ((u >> 16) & 1);   // round-to-nearest-even
    return (unsigned short)(u >> 16);
}
__device__ inline float bf2f(unsigned short u) {
    return __uint_as_float(((unsigned int)u) << 16);
}

#define GLD16(gp, lp)                                                                  \
    __builtin_amdgcn_global_load_lds(                                                  \
        (const __attribute__((address_space(1))) unsigned int*)(gp),                   \
        (__attribute__((address_space(3))) unsigned int*)(lp), 16, 0, 0)

// Stage a 128x64 bf16 tile into LDS with XOR swizzle: LDS[row][pg] holds
// global colgroup (pg ^ (row&7)) (colgroups of 8 el).  Fragment reads use
// pg = cg ^ (row&7), spreading the 16 m-lanes across 8 bank groups.
__device__ inline void stage128x64(const unsigned short* __restrict__ g, size_t ld,
                                   unsigned short* __restrict__ lds,
                                   int w, int lane)
{
    const int r8 = lane >> 3;                  // 0..7
    const int cg = (lane & 7) ^ r8;            // swizzled source colgroup
    const unsigned short* gp = g + (size_t)(w * 8 + r8) * ld + cg * 8;
    unsigned short* lp = lds + (size_t)(w * 8) * 64;
    #pragma unroll
    for (int seg = 0; seg < 4; ++seg)
        GLD16(gp + (size_t)(seg * 32) * ld, lp + (size_t)seg * 32 * 64);
}

// ---------------------------------------------------------------------------
// K0: cast fp32 -> bf16 for x, Wq, Wk, Wv
// ---------------------------------------------------------------------------
__global__ __launch_bounds__(256) void cast_all(
    const float* __restrict__ x, const float* __restrict__ Wq,
    const float* __restrict__ Wk, const float* __restrict__ Wv,
    unsigned short* __restrict__ xb, unsigned short* __restrict__ wqb,
    unsigned short* __restrict__ wkb, unsigned short* __restrict__ wvb)
{
    const float* src; unsigned short* dst; int n4;
    if (blockIdx.z == 0)      { src = x;  dst = xb;  n4 = (int)((size_t)NB * S_LEN * DK / 4); }
    else if (blockIdx.z == 1) { src = Wq; dst = wqb; n4 = DK * DK / 4; }
    else if (blockIdx.z == 2) { src = Wk; dst = wkb; n4 = DK * DK / 4; }
    else                      { src = Wv; dst = wvb; n4 = DK * DK / 4; }
    const int stride = gridDim.x * 256;
    for (int i = blockIdx.x * 256 + threadIdx.x; i < n4; i += stride) {
        float4 f = ((const float4*)src)[i];
        ushort4v o;
        o.x = f2bf(f.x); o.y = f2bf(f.y); o.z = f2bf(f.z); o.w = f2bf(f.w);
        ((ushort4v*)dst)[i] = o;
    }
}

// ---------------------------------------------------------------------------
// K1: fused QKV projection, bf16 MFMA, 128x128 tile, BK=64, swizzled LDS.
// z==2 (v) writes TRANSPOSED vT[b][o][s].
// COMPUTE-SKIP: for z<2 (q,k), m-tiles whose tokens are all >= len[b] skip
// the K-loop (their downstream consumers are constant-skipped or discarded
// in score's epilogue).  The epilogue still writes (bias-only values), so
// every byte of q/k is written on every launch — length-INDEPENDENT writes.
// ---------------------------------------------------------------------------
__global__ __launch_bounds__(256) void qkv_mfma(
    const unsigned short* __restrict__ xb,
    const unsigned short* __restrict__ wqb, const unsigned short* __restrict__ wkb,
    const unsigned short* __restrict__ wvb,
    const float* __restrict__ bq, const float* __restrict__ bk, const float* __restrict__ bv,
    const int* __restrict__ lengths,
    unsigned short* __restrict__ qb, unsigned short* __restrict__ kb,
    unsigned short* __restrict__ vTb)
{
    __shared__ unsigned short As[128 * 64];
    __shared__ unsigned short Bs[128 * 64];
    const int tid  = threadIdx.x;
    const int w    = tid >> 6, lane = tid & 63;
    const int lm   = lane & 15, quad = lane >> 4;
    const int xr   = lm & 7;                   // row&7 of every fragment row this lane reads
    const int m0   = blockIdx.x * 128, n0 = blockIdx.y * 128;
    const int z    = blockIdx.z;
    const unsigned short* Wb = (z == 0) ? wqb : (z == 1) ? wkb : wvb;
    const float* bias        = (z == 0) ? bq  : (z == 1) ? bk  : bv;

    const int bidx = m0 >> 11;                 // batch of this 128-tile
    const int len  = lengths[bidx];
    const int sm0  = m0 & (S_LEN - 1);
    const bool do_compute = (z == 2) || (sm0 < len);

    const unsigned short* Ag = xb + (size_t)m0 * DK;
    const unsigned short* Bg = Wb + (size_t)n0 * DK;

    const int wr = (w >> 1) * 64, wc = (w & 1) * 64;

    floatx4 acc[4][4];
    #pragma unroll
    for (int r = 0; r < 4; ++r)
        #pragma unroll
        for (int c = 0; c < 4; ++c) acc[r][c] = (floatx4)0.0f;

    if (do_compute) {
        for (int k0 = 0; k0 < DK; k0 += 64) {
            stage128x64(Ag + k0, DK, As, w, lane);
            stage128x64(Bg + k0, DK, Bs, w, lane);
            __syncthreads();
            #pragma unroll
            for (int ks = 0; ks < 2; ++ks) {
                short8 af[4], bf[4];
                #pragma unroll
                for (int r = 0; r < 4; ++r)
                    af[r] = *(const short8*)&As[(size_t)(wr + r*16 + lm) * 64 + ((((ks<<2)|quad) ^ xr) << 3)];
                #pragma unroll
                for (int c = 0; c < 4; ++c)
                    bf[c] = *(const short8*)&Bs[(size_t)(wc + c*16 + lm) * 64 + ((((ks<<2)|quad) ^ xr) << 3)];
                #pragma unroll
                for (int r = 0; r < 4; ++r)
                    #pragma unroll
                    for (int c = 0; c < 4; ++c)
                        acc[r][c] = __builtin_amdgcn_mfma_f32_16x16x32_bf16(af[r], bf[c], acc[r][c], 0, 0, 0);
            }
            __syncthreads();
        }
    }

    if (z < 2) {
        unsigned short* out = (z == 0) ? qb : kb;
        #pragma unroll
        for (int r = 0; r < 4; ++r) {
            const int gm = m0 + wr + r * 16 + quad * 4;
            #pragma unroll
            for (int c = 0; c < 4; ++c) {
                const int gn = n0 + wc + c * 16 + lm;
                const float bb = bias[gn];
                #pragma unroll
                for (int e = 0; e < 4; ++e)
                    out[(size_t)(gm + e) * DK + gn] = f2bf(acc[r][c][e] + bb);
            }
        }
    } else {
        #pragma unroll
        for (int r = 0; r < 4; ++r) {
            const int gm = m0 + wr + r * 16 + quad * 4;
            const int sm = gm & (S_LEN - 1);
            #pragma unroll
            for (int c = 0; c < 4; ++c) {
                const int gn = n0 + wc + c * 16 + lm;
                const float bb = bias[gn];
                ushort4v pk;
                pk.x = f2bf(acc[r][c][0] + bb);
                pk.y = f2bf(acc[r][c][1] + bb);
                pk.z = f2bf(acc[r][c][2] + bb);
                pk.w = f2bf(acc[r][c][3] + bb);
                *(ushort4v*)&vTb[((size_t)bidx * DK + gn) * S_LEN + sm] = pk;
            }
        }
    }
}

// ---------------------------------------------------------------------------
// K2: scores -> unnormalized probabilities u, bf16 out.
// Compact triangular grid: blockIdx.x = t in [0,136) maps to (bi,bj), bj<=bi.
// Epilogue writes u = exp(s/32) with:
//   j >  i          : 0   (causal)
//   i >= len, j <= i: 1   (-> uniform after row normalization)
// COMPUTE-SKIP: tiles with m0>=len or n0>=len consist ENTIRELY of the two
// constant cases above (gn<=i && i<len implies gn<len), so the K-loop is
// skipped; the epilogue writes the identical bytes either way.
// Coverage is all lower-triangle tiles, length-INDEPENDENT.
// ---------------------------------------------------------------------------
__global__ __launch_bounds__(256) void score_mfma(
    const unsigned short* __restrict__ qb, const unsigned short* __restrict__ kb,
    unsigned short* __restrict__ ub, const int* __restrict__ lengths)
{
    const int t = blockIdx.x, b = blockIdx.y;
    int bi = (int)((sqrtf(8.0f * t + 1.0f) - 1.0f) * 0.5f);
    while ((bi + 1) * (bi + 2) / 2 <= t) ++bi;
    while (bi * (bi + 1) / 2 > t) --bi;
    const int bj = t - bi * (bi + 1) / 2;
    const int m0 = bi * 128, n0 = bj * 128;
    const int len = lengths[b];

    __shared__ unsigned short As[128 * 64];
    __shared__ unsigned short Bs[128 * 64];
    const int tid  = threadIdx.x;
    const int w    = tid >> 6, lane = tid & 63;
    const int lm   = lane & 15, quad = lane >> 4;
    const int xr   = lm & 7;
    const unsigned short* Ag = qb + (size_t)b * S_LEN * DK + (size_t)m0 * DK;
    const unsigned short* Bg = kb + (size_t)b * S_LEN * DK + (size_t)n0 * DK;
    unsigned short* Ub = ub + (size_t)b * S_LEN * S_LEN;

    const int wr = (w >> 1) * 64, wc = (w & 1) * 64;

    floatx4 acc[4][4];
    #pragma unroll
    for (int r = 0; r < 4; ++r)
        #pragma unroll
        for (int c = 0; c < 4; ++c) acc[r][c] = (floatx4)0.0f;

    if (m0 < len && n0 < len) {
        for (int k0 = 0; k0 < DK; k0 += 64) {
            stage128x64(Ag + k0, DK, As, w, lane);
            stage128x64(Bg + k0, DK, Bs, w, lane);
            __syncthreads();
            #pragma unroll
            for (int ks = 0; ks < 2; ++ks) {
                short8 af[4], bf[4];
                #pragma unroll
                for (int r = 0; r < 4; ++r)
                    af[r] = *(const short8*)&As[(size_t)(wr + r*16 + lm) * 64 + ((((ks<<2)|quad) ^ xr) << 3)];
                #pragma unroll
                for (int c = 0; c < 4; ++c)
                    bf[c] = *(const short8*)&Bs[(size_t)(wc + c*16 + lm) * 64 + ((((ks<<2)|quad) ^ xr) << 3)];
                #pragma unroll
                for (int r = 0; r < 4; ++r)
                    #pragma unroll
                    for (int c = 0; c < 4; ++c)
                        acc[r][c] = __builtin_amdgcn_mfma_f32_16x16x32_bf16(af[r], bf[c], acc[r][c], 0, 0, 0);
            }
            __syncthreads();
        }
    }

    #pragma unroll
    for (int r = 0; r < 4; ++r) {
        const int gm = m0 + wr + r * 16 + quad * 4;
        #pragma unroll
        for (int c = 0; c < 4; ++c) {
            const int gn = n0 + wc + c * 16 + lm;
            #pragma unroll
            for (int e = 0; e < 4; ++e) {
                const int i = gm + e;
                float u;
                if (gn > i)          u = 0.0f;
                else if (i >= len)   u = 1.0f;
                else                 u = __expf(acc[r][c][e] * 0.03125f);
                Ub[(size_t)i * S_LEN + gn] = f2bf(u);
            }
        }
    }
}

// ---------------------------------------------------------------------------
// K3: deterministic per-row sum of u over [0, jend) -> inv_l[row] = 1/sum.
// ---------------------------------------------------------------------------
__global__ __launch_bounds__(256) void row_sum(
    const unsigned short* __restrict__ ub, float* __restrict__ inv_l)
{
    const int row = blockIdx.x;              // 0 .. B*S-1
    const int i = row & (S_LEN - 1);
    const int jend = ((i >> 7) + 1) << 7;
    const unsigned short* p = ub + (size_t)row * S_LEN;
    const int t = threadIdx.x;
    const int j0 = t * 8;

    float s = 0.0f;
    if (j0 < jend) {
        ushort8v raw = *(const ushort8v*)&p[j0];
        #pragma unroll
        for (int e = 0; e < 8; ++e) s += bf2f(raw[e]);
    }

    __shared__ float red[256];
    red[t] = s; __syncthreads();
    #pragma unroll
    for (int s2 = 128; s2 > 0; s2 >>= 1) {
        if (t < s2) red[t] += red[t + s2];
        __syncthreads();
    }
    if (t == 0) inv_l[row] = 1.0f / red[0];
}

// ---------------------------------------------------------------------------
// K4: O[b][i][o] = inv_l[b*S+i] * sum_j u[b][i][j] vT[b][o][j], bf16 MFMA.
// K-loop capped at (bi+1)*128 (u zero for j>i within that range).
// ---------------------------------------------------------------------------
__global__ __launch_bounds__(256) void pv_mfma(
    const unsigned short* __restrict__ ub, const unsigned short* __restrict__ vTb,
    const float* __restrict__ inv_l, float* __restrict__ out)
{
    __shared__ unsigned short As[128 * 64];
    __shared__ unsigned short Bs[128 * 64];
    const int tid  = threadIdx.x;
    const int w    = tid >> 6, lane = tid & 63;
    const int lm   = lane & 15, quad = lane >> 4;
    const int xr   = lm & 7;
    const int bi = blockIdx.x, bn = blockIdx.y, b = blockIdx.z;
    const int m0 = bi * 128, n0 = bn * 128;
    const unsigned short* Ag = ub  + (size_t)b * S_LEN * S_LEN + (size_t)m0 * S_LEN;
    const unsigned short* Bg = vTb + (size_t)b * DK * S_LEN    + (size_t)n0 * S_LEN;

    const int wr = (w >> 1) * 64, wc = (w & 1) * 64;
    const int kend = (bi + 1) * 128;

    floatx4 acc[4][4];
    #pragma unroll
    for (int r = 0; r < 4; ++r)
        #pragma unroll
        for (int c = 0; c < 4; ++c) acc[r][c] = (floatx4)0.0f;

    for (int k0 = 0; k0 < kend; k0 += 64) {
        stage128x64(Ag + k0, S_LEN, As, w, lane);
        stage128x64(Bg + k0, S_LEN, Bs, w, lane);
        __syncthreads();
        #pragma unroll
        for (int ks = 0; ks < 2; ++ks) {
            short8 af[4], bf[4];
            #pragma unroll
            for (int r = 0; r < 4; ++r)
                af[r] = *(const short8*)&As[(size_t)(wr + r*16 + lm) * 64 + ((((ks<<2)|quad) ^ xr) << 3)];
            #pragma unroll
            for (int c = 0; c < 4; ++c)
                bf[c] = *(const short8*)&Bs[(size_t)(wc + c*16 + lm) * 64 + ((((ks<<2)|quad) ^ xr) << 3)];
            #pragma unroll
            for (int r = 0; r < 4; ++r)
                #pragma unroll
                for (int c = 0; c < 4; ++c)
                    acc[r][c] = __builtin_amdgcn_mfma_f32_16x16x32_bf16(af[r], bf[c], acc[r][c], 0, 0, 0);
        }
        __syncthreads();
    }

    #pragma unroll
    for (int r = 0; r < 4; ++r) {
        const int gm = m0 + wr + r * 16 + quad * 4;
        const float4 il = *(const float4*)&inv_l[(size_t)b * S_LEN + gm];
        const float ilv[4] = {il.x, il.y, il.z, il.w};
        #pragma unroll
        for (int c = 0; c < 4; ++c) {
            const int gn = n0 + wc + c * 16 + lm;
            #pragma unroll
            for (int e = 0; e < 4; ++e)
                out[((size_t)b * S_LEN + gm + e) * DK + gn] = acc[r][c][e] * ilv[e];
        }
    }
}

// ---------------------------------------------------------------------------
extern "C" void kernel_launch(void* const* d_in, const int* in_sizes, int n_in,
                              void* d_out, int out_size, void* d_ws, size_t ws_size,
                              hipStream_t stream)
{
    const float* x  = (const float*)d_in[0];
    const float* Wq = (const float*)d_in[1];
    const float* bq = (const float*)d_in[2];
    const float* Wk = (const float*)d_in[3];
    const float* bk = (const float*)d_in[4];
    const float* Wv = (const float*)d_in[5];
    const float* bv = (const float*)d_in[6];
    const int* lengths = (const int*)d_in[7];
    float* out = (float*)d_out;

    // workspace (bf16 elements): qb | kb | vTb | xb | Wqb | Wkb | Wvb | ub | inv_l
    const size_t NQ = (size_t)NB * S_LEN * DK;       // 8388608
    const size_t NW = (size_t)DK * DK;               // 1048576
    const size_t NP = (size_t)NB * S_LEN * S_LEN;    // 16777216
    unsigned short* ws16 = (unsigned short*)d_ws;
    unsigned short* qb  = ws16;
    unsigned short* kb_ = ws16 + NQ;
    unsigned short* vTb = ws16 + 2 * NQ;
    unsigned short* xb  = ws16 + 3 * NQ;
    unsigned short* wqb = ws16 + 4 * NQ;
    unsigned short* wkb = wqb + NW;
    unsigned short* wvb = wkb + NW;
    unsigned short* ub  = ws16 + 4 * NQ + 3 * NW;    // bf16 unnormalized probs
    float* inv_l = (float*)(ub + NP);                // 8192 fp32

    cast_all<<<dim3(1024, 1, 4), 256, 0, stream>>>(x, Wq, Wk, Wv, xb, wqb, wkb, wvb);
    qkv_mfma<<<dim3(64, 8, 3), 256, 0, stream>>>(xb, wqb, wkb, wvb, bq, bk, bv, lengths,
                                                 qb, kb_, vTb);
    score_mfma<<<dim3(136, NB), 256, 0, stream>>>(qb, kb_, ub, lengths);
    row_sum<<<dim3(NB * S_LEN), 256, 0, stream>>>(ub, inv_l);
    pv_mfma<<<dim3(16, 8, NB), 256, 0, stream>>>(ub, vTb, inv_l, out);
}

// Round 7
// 219.594 us; speedup vs baseline: 1.1572x; 1.0351x over previous
//
#include <hip/hip_runtime.h>
#include <cstddef>
#include <cstdint>

#define NB 4
#define S_LEN 2048
#define DK 1024

typedef __attribute__((ext_vector_type(8))) short short8;       // 8 bf16 = 4 VGPR (MFMA A/B frag)
typedef __attribute__((ext_vector_type(4))) float floatx4;      // MFMA C/D frag
typedef __attribute__((ext_vector_type(4))) unsigned short ushort4v;
typedef __attribute__((ext_vector_type(8))) unsigned short ushort8v;

__device__ inline unsigned short f2bf(float f) {
    unsigned int u = __float_as_uint(f);
    u += 0x7fff + ((u >> 16) & 1);   // round-to-nearest-even
    return (unsigned short)(u >> 16);
}
__device__ inline float bf2f(unsigned short u) {
    return __uint_as_float(((unsigned int)u) << 16);
}

#define GLD16(gp, lp)                                                                  \
    __builtin_amdgcn_global_load_lds(                                                  \
        (const __attribute__((address_space(1))) unsigned int*)(gp),                   \
        (__attribute__((address_space(3))) unsigned int*)(lp), 16, 0, 0)

// Stage a 128x64 bf16 tile into LDS with XOR swizzle: LDS[row][pg] holds
// global colgroup (pg ^ (row&7)) (colgroups of 8 el).  Fragment reads use
// pg = cg ^ (row&7), spreading the 16 m-lanes across 8 bank groups.
__device__ inline void stage128x64(const unsigned short* __restrict__ g, size_t ld,
                                   unsigned short* __restrict__ lds,
                                   int w, int lane)
{
    const int r8 = lane >> 3;                  // 0..7
    const int cg = (lane & 7) ^ r8;            // swizzled source colgroup
    const unsigned short* gp = g + (size_t)(w * 8 + r8) * ld + cg * 8;
    unsigned short* lp = lds + (size_t)(w * 8) * 64;
    #pragma unroll
    for (int seg = 0; seg < 4; ++seg)
        GLD16(gp + (size_t)(seg * 32) * ld, lp + (size_t)seg * 32 * 64);
}

// ---------------------------------------------------------------------------
// K0: cast fp32 -> bf16 for x, Wq, Wk, Wv
// ---------------------------------------------------------------------------
__global__ __launch_bounds__(256) void cast_all(
    const float* __restrict__ x, const float* __restrict__ Wq,
    const float* __restrict__ Wk, const float* __restrict__ Wv,
    unsigned short* __restrict__ xb, unsigned short* __restrict__ wqb,
    unsigned short* __restrict__ wkb, unsigned short* __restrict__ wvb)
{
    const float* src; unsigned short* dst; int n4;
    if (blockIdx.z == 0)      { src = x;  dst = xb;  n4 = (int)((size_t)NB * S_LEN * DK / 4); }
    else if (blockIdx.z == 1) { src = Wq; dst = wqb; n4 = DK * DK / 4; }
    else if (blockIdx.z == 2) { src = Wk; dst = wkb; n4 = DK * DK / 4; }
    else                      { src = Wv; dst = wvb; n4 = DK * DK / 4; }
    const int stride = gridDim.x * 256;
    for (int i = blockIdx.x * 256 + threadIdx.x; i < n4; i += stride) {
        float4 f = ((const float4*)src)[i];
        ushort4v o;
        o.x = f2bf(f.x); o.y = f2bf(f.y); o.z = f2bf(f.z); o.w = f2bf(f.w);
        ((ushort4v*)dst)[i] = o;
    }
}

// ---------------------------------------------------------------------------
// K1: fused QKV projection, bf16 MFMA, 128x128 tile, BK=64, swizzled LDS.
// z==2 (v) writes TRANSPOSED vT[b][o][s].
// COMPUTE-SKIP: for z<2 (q,k), m-tiles whose tokens are all >= len[b] skip
// the K-loop; the epilogue still writes (bias-only values) so every byte of
// q/k is written on every launch — length-INDEPENDENT writes.
// ---------------------------------------------------------------------------
__global__ __launch_bounds__(256) void qkv_mfma(
    const unsigned short* __restrict__ xb,
    const unsigned short* __restrict__ wqb, const unsigned short* __restrict__ wkb,
    const unsigned short* __restrict__ wvb,
    const float* __restrict__ bq, const float* __restrict__ bk, const float* __restrict__ bv,
    const int* __restrict__ lengths,
    unsigned short* __restrict__ qb, unsigned short* __restrict__ kb,
    unsigned short* __restrict__ vTb)
{
    __shared__ unsigned short As[128 * 64];
    __shared__ unsigned short Bs[128 * 64];
    const int tid  = threadIdx.x;
    const int w    = tid >> 6, lane = tid & 63;
    const int lm   = lane & 15, quad = lane >> 4;
    const int xr   = lm & 7;                   // row&7 of every fragment row this lane reads
    const int m0   = blockIdx.x * 128, n0 = blockIdx.y * 128;
    const int z    = blockIdx.z;
    const unsigned short* Wb = (z == 0) ? wqb : (z == 1) ? wkb : wvb;
    const float* bias        = (z == 0) ? bq  : (z == 1) ? bk  : bv;

    const int bidx = m0 >> 11;                 // batch of this 128-tile
    const int len  = lengths[bidx];
    const int sm0  = m0 & (S_LEN - 1);
    const bool do_compute = (z == 2) || (sm0 < len);

    const unsigned short* Ag = xb + (size_t)m0 * DK;
    const unsigned short* Bg = Wb + (size_t)n0 * DK;

    const int wr = (w >> 1) * 64, wc = (w & 1) * 64;

    floatx4 acc[4][4];
    #pragma unroll
    for (int r = 0; r < 4; ++r)
        #pragma unroll
        for (int c = 0; c < 4; ++c) acc[r][c] = (floatx4)0.0f;

    if (do_compute) {
        for (int k0 = 0; k0 < DK; k0 += 64) {
            stage128x64(Ag + k0, DK, As, w, lane);
            stage128x64(Bg + k0, DK, Bs, w, lane);
            __syncthreads();
            #pragma unroll
            for (int ks = 0; ks < 2; ++ks) {
                short8 af[4], bf[4];
                #pragma unroll
                for (int r = 0; r < 4; ++r)
                    af[r] = *(const short8*)&As[(size_t)(wr + r*16 + lm) * 64 + ((((ks<<2)|quad) ^ xr) << 3)];
                #pragma unroll
                for (int c = 0; c < 4; ++c)
                    bf[c] = *(const short8*)&Bs[(size_t)(wc + c*16 + lm) * 64 + ((((ks<<2)|quad) ^ xr) << 3)];
                #pragma unroll
                for (int r = 0; r < 4; ++r)
                    #pragma unroll
                    for (int c = 0; c < 4; ++c)
                        acc[r][c] = __builtin_amdgcn_mfma_f32_16x16x32_bf16(af[r], bf[c], acc[r][c], 0, 0, 0);
            }
            __syncthreads();
        }
    }

    if (z < 2) {
        unsigned short* out = (z == 0) ? qb : kb;
        #pragma unroll
        for (int r = 0; r < 4; ++r) {
            const int gm = m0 + wr + r * 16 + quad * 4;
            #pragma unroll
            for (int c = 0; c < 4; ++c) {
                const int gn = n0 + wc + c * 16 + lm;
                const float bb = bias[gn];
                #pragma unroll
                for (int e = 0; e < 4; ++e)
                    out[(size_t)(gm + e) * DK + gn] = f2bf(acc[r][c][e] + bb);
            }
        }
    } else {
        #pragma unroll
        for (int r = 0; r < 4; ++r) {
            const int gm = m0 + wr + r * 16 + quad * 4;
            const int sm = gm & (S_LEN - 1);
            #pragma unroll
            for (int c = 0; c < 4; ++c) {
                const int gn = n0 + wc + c * 16 + lm;
                const float bb = bias[gn];
                ushort4v pk;
                pk.x = f2bf(acc[r][c][0] + bb);
                pk.y = f2bf(acc[r][c][1] + bb);
                pk.z = f2bf(acc[r][c][2] + bb);
                pk.w = f2bf(acc[r][c][3] + bb);
                *(ushort4v*)&vTb[((size_t)bidx * DK + gn) * S_LEN + sm] = pk;
            }
        }
    }
}

// ---------------------------------------------------------------------------
// K2: scores -> unnormalized probabilities u, bf16 out.
// Compact triangular grid: blockIdx.x = t in [0,136) maps to (bi,bj), bj<=bi.
// Epilogue writes u = exp(s/32) with:
//   j >  i          : 0   (causal)
//   i >= len, j <= i: 1   (-> uniform after row normalization)
// COMPUTE-SKIP: tiles with m0>=len or n0>=len are entirely the two constant
// cases; K-loop skipped, epilogue writes identical bytes either way.
// ---------------------------------------------------------------------------
__global__ __launch_bounds__(256) void score_mfma(
    const unsigned short* __restrict__ qb, const unsigned short* __restrict__ kb,
    unsigned short* __restrict__ ub, const int* __restrict__ lengths)
{
    const int t = blockIdx.x, b = blockIdx.y;
    int bi = (int)((sqrtf(8.0f * t + 1.0f) - 1.0f) * 0.5f);
    while ((bi + 1) * (bi + 2) / 2 <= t) ++bi;
    while (bi * (bi + 1) / 2 > t) --bi;
    const int bj = t - bi * (bi + 1) / 2;
    const int m0 = bi * 128, n0 = bj * 128;
    const int len = lengths[b];

    __shared__ unsigned short As[128 * 64];
    __shared__ unsigned short Bs[128 * 64];
    const int tid  = threadIdx.x;
    const int w    = tid >> 6, lane = tid & 63;
    const int lm   = lane & 15, quad = lane >> 4;
    const int xr   = lm & 7;
    const unsigned short* Ag = qb + (size_t)b * S_LEN * DK + (size_t)m0 * DK;
    const unsigned short* Bg = kb + (size_t)b * S_LEN * DK + (size_t)n0 * DK;
    unsigned short* Ub = ub + (size_t)b * S_LEN * S_LEN;

    const int wr = (w >> 1) * 64, wc = (w & 1) * 64;

    floatx4 acc[4][4];
    #pragma unroll
    for (int r = 0; r < 4; ++r)
        #pragma unroll
        for (int c = 0; c < 4; ++c) acc[r][c] = (floatx4)0.0f;

    if (m0 < len && n0 < len) {
        for (int k0 = 0; k0 < DK; k0 += 64) {
            stage128x64(Ag + k0, DK, As, w, lane);
            stage128x64(Bg + k0, DK, Bs, w, lane);
            __syncthreads();
            #pragma unroll
            for (int ks = 0; ks < 2; ++ks) {
                short8 af[4], bf[4];
                #pragma unroll
                for (int r = 0; r < 4; ++r)
                    af[r] = *(const short8*)&As[(size_t)(wr + r*16 + lm) * 64 + ((((ks<<2)|quad) ^ xr) << 3)];
                #pragma unroll
                for (int c = 0; c < 4; ++c)
                    bf[c] = *(const short8*)&Bs[(size_t)(wc + c*16 + lm) * 64 + ((((ks<<2)|quad) ^ xr) << 3)];
                #pragma unroll
                for (int r = 0; r < 4; ++r)
                    #pragma unroll
                    for (int c = 0; c < 4; ++c)
                        acc[r][c] = __builtin_amdgcn_mfma_f32_16x16x32_bf16(af[r], bf[c], acc[r][c], 0, 0, 0);
            }
            __syncthreads();
        }
    }

    #pragma unroll
    for (int r = 0; r < 4; ++r) {
        const int gm = m0 + wr + r * 16 + quad * 4;
        #pragma unroll
        for (int c = 0; c < 4; ++c) {
            const int gn = n0 + wc + c * 16 + lm;
            #pragma unroll
            for (int e = 0; e < 4; ++e) {
                const int i = gm + e;
                float u;
                if (gn > i)          u = 0.0f;
                else if (i >= len)   u = 1.0f;
                else                 u = __expf(acc[r][c][e] * 0.03125f);
                Ub[(size_t)i * S_LEN + gn] = f2bf(u);
            }
        }
    }
}

// ---------------------------------------------------------------------------
// K3: O[b][i][o] = (1/l_i) * sum_j u[b][i][j] vT[b][o][j], bf16 MFMA.
// K-loop capped at (bi+1)*128 (u zero for j>i within that range).
// ROW SUMS COMPUTED IN-KERNEL: each lane accumulates sum of its A-fragment
// elements (u values) across the K-loop; deterministic cross-quad shuffle
// butterfly completes each row's sum; waves 0 and 3 publish rows 0-63 /
// 64-127 to LDS; epilogue scales by 1/l.  This replaces the row_sum kernel
// (the block's K-range [0,kend) covers every nonzero u of its rows, so the
// sum is exact).
// ---------------------------------------------------------------------------
__global__ __launch_bounds__(256) void pv_mfma(
    const unsigned short* __restrict__ ub, const unsigned short* __restrict__ vTb,
    float* __restrict__ out)
{
    __shared__ unsigned short As[128 * 64];
    __shared__ unsigned short Bs[128 * 64];
    __shared__ float sums_lds[128];
    const int tid  = threadIdx.x;
    const int w    = tid >> 6, lane = tid & 63;
    const int lm   = lane & 15, quad = lane >> 4;
    const int xr   = lm & 7;
    const int bi = blockIdx.x, bn = blockIdx.y, b = blockIdx.z;
    const int m0 = bi * 128, n0 = bn * 128;
    const unsigned short* Ag = ub  + (size_t)b * S_LEN * S_LEN + (size_t)m0 * S_LEN;
    const unsigned short* Bg = vTb + (size_t)b * DK * S_LEN    + (size_t)n0 * S_LEN;

    const int wr = (w >> 1) * 64, wc = (w & 1) * 64;
    const int kend = (bi + 1) * 128;

    floatx4 acc[4][4];
    #pragma unroll
    for (int r = 0; r < 4; ++r)
        #pragma unroll
        for (int c = 0; c < 4; ++c) acc[r][c] = (floatx4)0.0f;

    float srow[4] = {0.0f, 0.0f, 0.0f, 0.0f};   // partial row sums (row wr+r*16+lm)

    for (int k0 = 0; k0 < kend; k0 += 64) {
        stage128x64(Ag + k0, S_LEN, As, w, lane);
        stage128x64(Bg + k0, S_LEN, Bs, w, lane);
        __syncthreads();
        #pragma unroll
        for (int ks = 0; ks < 2; ++ks) {
            short8 af[4], bf[4];
            #pragma unroll
            for (int r = 0; r < 4; ++r)
                af[r] = *(const short8*)&As[(size_t)(wr + r*16 + lm) * 64 + ((((ks<<2)|quad) ^ xr) << 3)];
            #pragma unroll
            for (int c = 0; c < 4; ++c)
                bf[c] = *(const short8*)&Bs[(size_t)(wc + c*16 + lm) * 64 + ((((ks<<2)|quad) ^ xr) << 3)];
            #pragma unroll
            for (int r = 0; r < 4; ++r) {
                const ushort8v uu = *(const ushort8v*)&af[r];
                #pragma unroll
                for (int e = 0; e < 8; ++e) srow[r] += bf2f(uu[e]);
                #pragma unroll
                for (int c = 0; c < 4; ++c)
                    acc[r][c] = __builtin_amdgcn_mfma_f32_16x16x32_bf16(af[r], bf[c], acc[r][c], 0, 0, 0);
            }
        }
        __syncthreads();
    }

    // complete row sums across the 4 quads (deterministic butterfly)
    #pragma unroll
    for (int r = 0; r < 4; ++r) {
        srow[r] += __shfl_xor(srow[r], 16, 64);
        srow[r] += __shfl_xor(srow[r], 32, 64);
    }
    if ((w == 0 || w == 3) && quad == 0) {
        #pragma unroll
        for (int r = 0; r < 4; ++r) sums_lds[wr + r * 16 + lm] = srow[r];
    }
    __syncthreads();

    #pragma unroll
    for (int r = 0; r < 4; ++r) {
        const int lrow = wr + r * 16 + quad * 4;      // row within tile
        const int gm = m0 + lrow;
        float ilv[4];
        #pragma unroll
        for (int e = 0; e < 4; ++e) ilv[e] = 1.0f / sums_lds[lrow + e];
        #pragma unroll
        for (int c = 0; c < 4; ++c) {
            const int gn = n0 + wc + c * 16 + lm;
            #pragma unroll
            for (int e = 0; e < 4; ++e)
                out[((size_t)b * S_LEN + gm + e) * DK + gn] = acc[r][c][e] * ilv[e];
        }
    }
}

// ---------------------------------------------------------------------------
extern "C" void kernel_launch(void* const* d_in, const int* in_sizes, int n_in,
                              void* d_out, int out_size, void* d_ws, size_t ws_size,
                              hipStream_t stream)
{
    const float* x  = (const float*)d_in[0];
    const float* Wq = (const float*)d_in[1];
    const float* bq = (const float*)d_in[2];
    const float* Wk = (const float*)d_in[3];
    const float* bk = (const float*)d_in[4];
    const float* Wv = (const float*)d_in[5];
    const float* bv = (const float*)d_in[6];
    const int* lengths = (const int*)d_in[7];
    float* out = (float*)d_out;

    // workspace (bf16 elements): qb | kb | vTb | xb | Wqb | Wkb | Wvb | ub
    const size_t NQ = (size_t)NB * S_LEN * DK;       // 8388608
    const size_t NW = (size_t)DK * DK;               // 1048576
    unsigned short* ws16 = (unsigned short*)d_ws;
    unsigned short* qb  = ws16;
    unsigned short* kb_ = ws16 + NQ;
    unsigned short* vTb = ws16 + 2 * NQ;
    unsigned short* xb  = ws16 + 3 * NQ;
    unsigned short* wqb = ws16 + 4 * NQ;
    unsigned short* wkb = wqb + NW;
    unsigned short* wvb = wkb + NW;
    unsigned short* ub  = ws16 + 4 * NQ + 3 * NW;    // bf16 unnormalized probs

    cast_all<<<dim3(1024, 1, 4), 256, 0, stream>>>(x, Wq, Wk, Wv, xb, wqb, wkb, wvb);
    qkv_mfma<<<dim3(64, 8, 3), 256, 0, stream>>>(xb, wqb, wkb, wvb, bq, bk, bv, lengths,
                                                 qb, kb_, vTb);
    score_mfma<<<dim3(136, NB), 256, 0, stream>>>(qb, kb_, ub, lengths);
    pv_mfma<<<dim3(16, 8, NB), 256, 0, stream>>>(ub, vTb, out);
}